// Round 2
// baseline (449.333 us; speedup 1.0000x reference)
//
#include <hip/hip_runtime.h>
#include <hip/hip_bf16.h>

#define Bb 256
#define Ss 2048
#define Tt 48
#define BS 10            // steps per LDS pipeline block
#define NBLK 204         // full blocks (steps 1..2040)
#define TAILN 7          // tail steps (2041..2047)

static constexpr float C_SHIFT = 4.5f;   // prescale folded into exp(em - C)

typedef float f4  __attribute__((ext_vector_type(4)));
typedef short s4h __attribute__((ext_vector_type(4)));

__device__ __forceinline__ s4h mk_s4h(unsigned lo, unsigned hi) {
    union { unsigned u[2]; s4h v; } t; t.u[0] = lo; t.u[1] = hi; return t.v;
}

// truncating fp32->bf16 pair pack (hot loop)
__device__ __forceinline__ unsigned pk_trunc(float lo, float hi) {
    unsigned a = __builtin_bit_cast(unsigned, lo);
    unsigned b = __builtin_bit_cast(unsigned, hi);
#if __has_builtin(__builtin_amdgcn_perm)
    return __builtin_amdgcn_perm(b, a, 0x07060302u);
#else
    return (b & 0xFFFF0000u) | (a >> 16);
#endif
}

// RNE pack (prologue only)
__device__ __forceinline__ unsigned pk_rne(float lo, float hi) {
    __hip_bfloat162 h = __float22bfloat162_rn(make_float2(lo, hi));
    union { __hip_bfloat16 b[2]; unsigned u; } t;
    t.b[0] = h.x; t.b[1] = h.y;
    return t.u;
}

// ---------------------------------------------------------------------------
// One forward step: D = E^T(A) @ X(B) ; D *= e ; optional scale/renorm; repack
// C-layout of 16x16x16 == B-frag layout  ->  state stays in registers.
// ---------------------------------------------------------------------------
__device__ __forceinline__ void chain_step(const s4h (&A)[3][3], s4h (&X)[3], f4 (&D)[3],
                                           const f4 (&e)[3], float& rscale, float& acc,
                                           bool first, bool renorm, bool pack)
{
#pragma unroll
    for (int mp = 0; mp < 3; ++mp) {
        f4 c = {0.f, 0.f, 0.f, 0.f};
        c = __builtin_amdgcn_mfma_f32_16x16x16bf16_1k(A[mp][0], X[0], c, 0, 0, 0);
        c = __builtin_amdgcn_mfma_f32_16x16x16bf16_1k(A[mp][1], X[1], c, 0, 0, 0);
        c = __builtin_amdgcn_mfma_f32_16x16x16bf16_1k(A[mp][2], X[2], c, 0, 0, 0);
        D[mp] = c;
    }
#pragma unroll
    for (int mp = 0; mp < 3; ++mp) {
#pragma unroll
        for (int r = 0; r < 4; ++r) {
            float d = D[mp][r] * e[mp][r];
            if (first) d *= rscale;
            D[mp][r] = d;
        }
    }
    if (renorm) {
        float mx = D[0][0];
#pragma unroll
        for (int mp = 0; mp < 3; ++mp)
#pragma unroll
            for (int r = 0; r < 4; ++r) mx = fmaxf(mx, D[mp][r]);
        mx = fmaxf(mx, __shfl_xor(mx, 16));
        mx = fmaxf(mx, __shfl_xor(mx, 32));
        acc += __logf(mx);
        rscale = __builtin_amdgcn_rcpf(mx);
    }
    if (pack) {
#pragma unroll
        for (int mp = 0; mp < 3; ++mp)
            X[mp] = mk_s4h(pk_trunc(D[mp][0], D[mp][1]), pk_trunc(D[mp][2], D[mp][3]));
    }
}

// ---------------------------------------------------------------------------
// Producer: one wave loads 5 steps x 3 chunks (global, scattered 64B lines),
// applies exp(x - C), writes contiguous b128 pattern into the LDS ring.
// pb already includes the lane's g*16 offset.
// ---------------------------------------------------------------------------
__device__ __forceinline__ void produce(const char* __restrict__ pb, int l,
                                        float* __restrict__ dst, int sbase, int u0)
{
    f4 v[5][3];
#pragma unroll
    for (int u = 0; u < 5; ++u) {
        int s = sbase + u0 + u; if (s > Ss - 1) s = Ss - 1;
#pragma unroll
        for (int m = 0; m < 3; ++m)
            v[u][m] = *(const f4*)(pb + (size_t)s * (Tt * 4) + m * 64);
    }
#pragma unroll
    for (int u = 0; u < 5; ++u) {
#pragma unroll
        for (int m = 0; m < 3; ++m) {
            f4 e;
#pragma unroll
            for (int j = 0; j < 4; ++j) e[j] = __expf(v[u][m][j] - C_SHIFT);
            *(f4*)(dst + ((u0 + u) * 3 + m) * 256 + l * 4) = e;
        }
    }
}

// ---------------------------------------------------------------------------
// Consumer: NS steps from one LDS block, 1-step register prefetch of e.
// ---------------------------------------------------------------------------
template<int NS, bool LASTBLK>
__device__ __forceinline__ void consume_block(const float* __restrict__ srcf, int l,
                                              const s4h (&A)[3][3], s4h (&X)[3], f4 (&D)[3],
                                              float& rscale, float& acc)
{
    const f4* src = (const f4*)srcf;
    f4 e[3], en[3];
#pragma unroll
    for (int m = 0; m < 3; ++m) e[m] = src[m * 64 + l];
#pragma unroll
    for (int u = 0; u < NS; ++u) {
        if (u + 1 < NS) {
#pragma unroll
            for (int m = 0; m < 3; ++m) en[m] = src[((u + 1) * 3 + m) * 64 + l];
        }
        bool renorm = (!LASTBLK) && (u == NS - 1);
        bool pack   = !(LASTBLK && u == NS - 1);
        chain_step(A, X, D, e, rscale, acc, u == 0, renorm, pack);
#pragma unroll
        for (int m = 0; m < 3; ++m) e[m] = en[m];
    }
}

// ---------------------------------------------------------------------------
// Chain kernel: 16 blocks x 192 threads. Wave 0 = chain math (16 batches),
// waves 1-2 = producers filling the LDS ring one block ahead.
// ---------------------------------------------------------------------------
__global__ __launch_bounds__(192, 1)
void crf_chain(const float* __restrict__ em, const float* __restrict__ trn,
               const float* __restrict__ stt, const float* __restrict__ ent,
               float* __restrict__ fwd, float* __restrict__ outz)
{
    __shared__ float lds[2][BS * 3 * 256];   // 2 x 10 steps x 3KB = 60 KB
    const int tid = threadIdx.x;
    const int wv  = tid >> 6;                 // 0 consumer, 1..2 producers
    const int l = tid & 63, col = l & 15, g = l >> 4;
    const int w = blockIdx.x, b = w * 16 + col;
    const char* pb = (const char*)(em + (size_t)b * (Ss * Tt)) + g * 16;

    s4h A[3][3]; s4h X[3]; f4 D[3];
    float rscale = 1.0f, acc = 0.0f;

    if (wv == 0) {
        if (w == 0 && tid == 0) outz[0] = 0.0f;   // zero d_out for gold's atomics
        // A = exp(trans)^T fragments
#pragma unroll
        for (int mp = 0; mp < 3; ++mp) {
            const int jo = 16 * mp + col;
#pragma unroll
            for (int km = 0; km < 3; ++km) {
                float v0 = __expf(trn[(16 * km + 4 * g + 0) * Tt + jo]);
                float v1 = __expf(trn[(16 * km + 4 * g + 1) * Tt + jo]);
                float v2 = __expf(trn[(16 * km + 4 * g + 2) * Tt + jo]);
                float v3 = __expf(trn[(16 * km + 4 * g + 3) * Tt + jo]);
                A[mp][km] = mk_s4h(pk_rne(v0, v1), pk_rne(v2, v3));
            }
        }
        // X0[i][b] = exp(start_i + em[b][0][i] - C)
#pragma unroll
        for (int km = 0; km < 3; ++km) {
            f4 e = *(const f4*)(pb + km * 64);
            float v[4];
#pragma unroll
            for (int j = 0; j < 4; ++j)
                v[j] = __expf(e[j] - C_SHIFT) * __expf(stt[16 * km + 4 * g + j]);
            X[km] = mk_s4h(pk_rne(v[0], v[1]), pk_rne(v[2], v[3]));
        }
    } else {
        produce(pb, l, &lds[0][0], 1, (wv - 1) * 5);   // block 0 = steps 1..10
    }
    __syncthreads();

    for (int kb = 0; kb < NBLK; ++kb) {
        if (wv == 0) {
            consume_block<BS, false>(&lds[kb & 1][0], l, A, X, D, rscale, acc);
        } else {
            produce(pb, l, &lds[(kb + 1) & 1][0], BS * (kb + 1) + 1, (wv - 1) * 5);
        }
        __syncthreads();
    }

    if (wv == 0) {
        consume_block<TAILN, true>(&lds[NBLK & 1][0], l, A, X, D, rscale, acc);
        // fwd = log( sum_j D[j]*exp(end_j) ) + acc + S*C
        float part = 0.0f;
#pragma unroll
        for (int mp = 0; mp < 3; ++mp)
#pragma unroll
            for (int r = 0; r < 4; ++r)
                part = fmaf(D[mp][r], __expf(ent[16 * mp + 4 * g + r]), part);
        part += __shfl_xor(part, 16);
        part += __shfl_xor(part, 32);
        if (l < 16) fwd[b] = __logf(part) + acc + (float)Ss * C_SHIFT;
    }
}

// ---------------------------------------------------------------------------
// Gold score + final mean: one block per batch
// ---------------------------------------------------------------------------
__global__ __launch_bounds__(256)
void crf_gold(const float* __restrict__ em, const int* __restrict__ tags,
              const int* __restrict__ mask, const float* __restrict__ trn,
              const float* __restrict__ stt, const float* __restrict__ ent,
              const float* __restrict__ fwd, float* __restrict__ out)
{
    __shared__ float red[256];
    const int b = blockIdx.x, t = threadIdx.x;
    const int* tg = tags + (size_t)b * Ss;
    float local = 0.0f;
    for (int s = t; s < Ss; s += 256) {
        if (s > 0) {
            int pv = tg[s - 1], cu = tg[s];
            float mf = (float)mask[(size_t)b * Ss + s];
            local += (trn[pv * Tt + cu] + em[((size_t)b * Ss + s) * Tt + cu]) * mf;
        }
    }
    if (t == 0) {
        int t0 = tg[0];
        local += stt[t0] + em[(size_t)b * Ss * Tt + t0];
        local += ent[tg[Ss - 1]];
    }
    red[t] = local;
    __syncthreads();
    for (int off = 128; off > 0; off >>= 1) {
        if (t < off) red[t] += red[t + off];
        __syncthreads();
    }
    if (t == 0) atomicAdd(out, (fwd[b] - red[0]) * (1.0f / 256.0f));
}

// ---------------------------------------------------------------------------
extern "C" void kernel_launch(void* const* d_in, const int* in_sizes, int n_in,
                              void* d_out, int out_size, void* d_ws, size_t ws_size,
                              hipStream_t stream)
{
    const float* em  = (const float*)d_in[0];
    const int* tags  = (const int*)d_in[1];
    const int* mask  = (const int*)d_in[2];
    const float* trn = (const float*)d_in[3];
    const float* stt = (const float*)d_in[4];
    const float* ent = (const float*)d_in[5];
    float* out = (float*)d_out;
    float* fwd = (float*)d_ws;   // 256 floats of scratch only

    crf_chain<<<16, 192, 0, stream>>>(em, trn, stt, ent, fwd, out);
    crf_gold<<<256, 256, 0, stream>>>(em, tags, mask, trn, stt, ent, fwd, out);
}

// Round 3
// 266.636 us; speedup vs baseline: 1.6852x; 1.6852x over previous
//
#include <hip/hip_runtime.h>
#include <hip/hip_bf16.h>

#define Bb 256
#define Ss 2048
#define Tt 48
#define NCK 12           // chunks per batch
#define CLEN 171         // steps per chunk (last chunk: 166)

static constexpr float C_SHIFT = 4.875f;  // ~ln(48)+1: per-step growth ~= 1

typedef float f4  __attribute__((ext_vector_type(4)));
typedef short s4h __attribute__((ext_vector_type(4)));

__device__ __forceinline__ s4h mk_s4h(unsigned lo, unsigned hi) {
    union { unsigned u[2]; s4h v; } t; t.u[0] = lo; t.u[1] = hi; return t.v;
}
__device__ __forceinline__ unsigned pk_trunc(float lo, float hi) {
    unsigned a = __builtin_bit_cast(unsigned, lo);
    unsigned b = __builtin_bit_cast(unsigned, hi);
#if __has_builtin(__builtin_amdgcn_perm)
    return __builtin_amdgcn_perm(b, a, 0x07060302u);
#else
    return (b & 0xFFFF0000u) | (a >> 16);
#endif
}
__device__ __forceinline__ unsigned pk_rne(float lo, float hi) {
    __hip_bfloat162 h = __float22bfloat162_rn(make_float2(lo, hi));
    union { __hip_bfloat16 b[2]; unsigned u; } t;
    t.b[0] = h.x; t.b[1] = h.y;
    return t.u;
}
__device__ __forceinline__ float bfu(unsigned u) { return __builtin_bit_cast(float, u); }

#define MFMA16(a,b,c) __builtin_amdgcn_mfma_f32_16x16x16bf16_1k(a, b, c, 0, 0, 0)

__device__ __forceinline__ s4h scale_pack(f4 c, f4 e) {
    return mk_s4h(pk_trunc(c[0]*e[0], c[1]*e[1]), pk_trunc(c[2]*e[2], c[3]*e[3]));
}

// One scan step: Po = rowscale(E^T · Pi, e). eb points at this step's e, lane-offset g*4 applied.
__device__ __forceinline__ void scan_step(const s4h (&A)[3][3], const s4h (&Pi)[3][3],
                                          s4h (&Po)[3][3], const float* __restrict__ eb)
{
    f4 e[3];
#pragma unroll
    for (int mt = 0; mt < 3; ++mt) e[mt] = *(const f4*)(eb + mt * 16);
#pragma unroll
    for (int nt = 0; nt < 3; ++nt) {
        f4 c0 = {0.f,0.f,0.f,0.f}, c1 = {0.f,0.f,0.f,0.f}, c2 = {0.f,0.f,0.f,0.f};
#pragma unroll
        for (int kt = 0; kt < 3; ++kt) {
            c0 = MFMA16(A[0][kt], Pi[kt][nt], c0);
            c1 = MFMA16(A[1][kt], Pi[kt][nt], c1);
            c2 = MFMA16(A[2][kt], Pi[kt][nt], c2);
        }
        Po[0][nt] = scale_pack(c0, e[0]);
        Po[1][nt] = scale_pack(c1, e[1]);
        Po[2][nt] = scale_pack(c2, e[2]);
    }
}

// ---------------------------------------------------------------------------
// Phase 1: one wave per (batch, chunk) computes the chunk's 48x48 transfer
// matrix product in registers (C-layout == B-frag layout identity).
// 768 blocks x 256 threads = 3072 waves = 256 batches x 12 chunks.
// ---------------------------------------------------------------------------
__global__ __launch_bounds__(256, 3)
void crf_scan(const float* __restrict__ em, const float* __restrict__ trn,
              float* __restrict__ pws, float* __restrict__ outz)
{
    __shared__ float lex[4][16 * Tt];          // per-wave 16-step exp(em) buffer (3 KB)
    const int tid = threadIdx.x, wv = tid >> 6, l = tid & 63;
    const int c0 = l & 15, g = l >> 4;
    const int wid = blockIdx.x * 4 + wv;
    const int b = wid / NCK, ck = wid % NCK;
    if (blockIdx.x == 0 && tid == 0) outz[0] = 0.0f;   // zero d_out for finish's atomics

    // A = E^T as A-fragments: A[mt][kt] slot j = exp(trn[(16kt+4g+j)*48 + 16mt+c0])
    s4h A[3][3];
#pragma unroll
    for (int mt = 0; mt < 3; ++mt)
#pragma unroll
        for (int kt = 0; kt < 3; ++kt) {
            float v0 = __expf(trn[(16*kt + 4*g + 0) * Tt + 16*mt + c0]);
            float v1 = __expf(trn[(16*kt + 4*g + 1) * Tt + 16*mt + c0]);
            float v2 = __expf(trn[(16*kt + 4*g + 2) * Tt + 16*mt + c0]);
            float v3 = __expf(trn[(16*kt + 4*g + 3) * Tt + 16*mt + c0]);
            A[mt][kt] = mk_s4h(pk_rne(v0, v1), pk_rne(v2, v3));
        }

    // P = identity (B-frag layout): P[kt][nt] slot j = (kt==nt && 4g+j==c0)
    s4h P[3][3], Q[3][3];
#pragma unroll
    for (int kt = 0; kt < 3; ++kt)
#pragma unroll
        for (int nt = 0; nt < 3; ++nt) {
            s4h v;
#pragma unroll
            for (int j = 0; j < 4; ++j)
                v[j] = (short)((kt == nt && (4*g + j) == c0) ? 0x3F80 : 0);
            P[kt][nt] = v;
        }

    const int total = (ck == NCK - 1) ? (Ss - 1 - ck * CLEN) : CLEN;  // 171 or 166
    const int s0 = ck * CLEN + 1;
    const float* emb = em + (size_t)b * (Ss * Tt);
    float* lw = &lex[wv][0];
    const float* lexg = lw + g * 4;
    const int lim = Ss * Tt - 4;
    bool inQ = false;

    const int nsub = (total + 15) >> 4;
    for (int sub = 0; sub < nsub; ++sub) {
        // stage 16 steps of exp(em - C) into LDS (coalesced f4, clamped)
        f4 r[3];
#pragma unroll
        for (int i = 0; i < 3; ++i) {
            int o = (s0 + sub * 16) * Tt + l * 4 + i * 256;
            if (o > lim) o = lim;
            r[i] = *(const f4*)(emb + o);
        }
#pragma unroll
        for (int i = 0; i < 3; ++i)
#pragma unroll
            for (int j = 0; j < 4; ++j) r[i][j] = __expf(r[i][j] - C_SHIFT);
#pragma unroll
        for (int i = 0; i < 3; ++i) *(f4*)(lw + l * 4 + i * 256) = r[i];

        int nsteps = total - sub * 16; if (nsteps > 16) nsteps = 16;
        const int npair = nsteps >> 1;
        for (int p = 0; p < npair; ++p) {
            scan_step(A, P, Q, lexg + (2*p) * Tt);
            scan_step(A, Q, P, lexg + (2*p + 1) * Tt);
        }
        if (nsteps & 1) {                       // only possible on the last sub
            scan_step(A, P, Q, lexg + (nsteps - 1) * Tt);
            inQ = true;
        }
    }

    // store 9 frags (bf16 pairs) -> pws, coalesced 512B per frag
    uint2* pw = (uint2*)pws + (size_t)wid * 576 + l;
    const s4h (&F)[3][3] = inQ ? Q : P;
#pragma unroll
    for (int kt = 0; kt < 3; ++kt)
#pragma unroll
        for (int nt = 0; nt < 3; ++nt)
            pw[(kt*3 + nt) * 64] = __builtin_bit_cast(uint2, F[kt][nt]);
}

// ---------------------------------------------------------------------------
// Phase 2 + gold, merged: one block per batch. All 256 threads do the gold
// partial; wave 0 then runs the 12-step chunk-matvec scan and combines.
// ---------------------------------------------------------------------------
__global__ __launch_bounds__(256)
void crf_finish(const float* __restrict__ em, const int* __restrict__ tags,
                const int* __restrict__ mask, const float* __restrict__ trn,
                const float* __restrict__ stt, const float* __restrict__ ent,
                const float* __restrict__ pws, float* __restrict__ out)
{
    __shared__ float red[256];
    __shared__ float alpha[Tt];
    const int b = blockIdx.x, t = threadIdx.x;

    // gold partial
    const int* tg = tags + (size_t)b * Ss;
    float local = 0.0f;
    for (int s = t; s < Ss; s += 256) {
        if (s > 0) {
            int pv = tg[s - 1], cu = tg[s];
            float mf = (float)mask[(size_t)b * Ss + s];
            local += (trn[pv * Tt + cu] + em[((size_t)b * Ss + s) * Tt + cu]) * mf;
        }
    }
    if (t == 0) {
        int t0 = tg[0];
        local += stt[t0] + em[(size_t)b * Ss * Tt + t0];
        local += ent[tg[Ss - 1]];
    }
    red[t] = local;
    __syncthreads();
    if (t < 128) red[t] += red[t + 128];
    __syncthreads();

    if (t < 64) {
        const int l = t, c0 = l & 15, g = l >> 4;
        float gsum = red[l] + red[l + 64];
#pragma unroll
        for (int m = 32; m >= 1; m >>= 1) gsum += __shfl_xor(gsum, m);

        // init alpha = exp(stt + em[:,0,:] - C)
        if (l < Tt) alpha[l] = __expf(stt[l] + em[(size_t)b * Ss * Tt + l] - C_SHIFT);

        float acc = 0.0f;
        const uint2* pw = (const uint2*)pws + (size_t)b * NCK * 576 + l;
        for (int ck = 0; ck < NCK; ++ck) {
            uint2 fr[3][3];
#pragma unroll
            for (int kt = 0; kt < 3; ++kt)
#pragma unroll
                for (int nt = 0; nt < 3; ++nt)
                    fr[kt][nt] = pw[(size_t)ck * 576 + (kt*3 + nt) * 64];
            float av[3];
#pragma unroll
            for (int nt = 0; nt < 3; ++nt) av[nt] = alpha[16*nt + c0];
            float y[12];
#pragma unroll
            for (int i = 0; i < 12; ++i) y[i] = 0.0f;
#pragma unroll
            for (int kt = 0; kt < 3; ++kt)
#pragma unroll
                for (int nt = 0; nt < 3; ++nt) {
                    uint2 q = fr[kt][nt];
                    y[kt*4+0] += bfu(q.x << 16)          * av[nt];
                    y[kt*4+1] += bfu(q.x & 0xFFFF0000u)  * av[nt];
                    y[kt*4+2] += bfu(q.y << 16)          * av[nt];
                    y[kt*4+3] += bfu(q.y & 0xFFFF0000u)  * av[nt];
                }
            // sum over columns (lanes differing in bits 0..3)
#pragma unroll
            for (int m = 1; m <= 8; m <<= 1)
#pragma unroll
                for (int i = 0; i < 12; ++i) y[i] += __shfl_xor(y[i], m);
            // renorm
            float mx = y[0];
#pragma unroll
            for (int i = 1; i < 12; ++i) mx = fmaxf(mx, y[i]);
            mx = fmaxf(mx, __shfl_xor(mx, 16));
            mx = fmaxf(mx, __shfl_xor(mx, 32));
            acc += __logf(mx);
            float rm = 1.0f / mx;
            if (c0 == 0) {
#pragma unroll
                for (int kt = 0; kt < 3; ++kt)
#pragma unroll
                    for (int j = 0; j < 4; ++j)
                        alpha[16*kt + 4*g + j] = y[kt*4 + j] * rm;
            }
        }
        // fwd = log(sum alpha * exp(ent)) + acc + 2048*C
        float part = (l < Tt) ? alpha[l] * __expf(ent[l]) : 0.0f;
#pragma unroll
        for (int m = 32; m >= 1; m >>= 1) part += __shfl_xor(part, m);
        if (t == 0) {
            float fwd = __logf(part) + acc + (float)Ss * C_SHIFT;
            atomicAdd(out, (fwd - gsum) * (1.0f / 256.0f));
        }
    }
}

// ---------------------------------------------------------------------------
extern "C" void kernel_launch(void* const* d_in, const int* in_sizes, int n_in,
                              void* d_out, int out_size, void* d_ws, size_t ws_size,
                              hipStream_t stream)
{
    const float* em  = (const float*)d_in[0];
    const int* tags  = (const int*)d_in[1];
    const int* mask  = (const int*)d_in[2];
    const float* trn = (const float*)d_in[3];
    const float* stt = (const float*)d_in[4];
    const float* ent = (const float*)d_in[5];
    float* out = (float*)d_out;
    float* pws = (float*)d_ws;   // 3072 waves x 576 uint2 = ~14.2 MB

    crf_scan<<<768, 256, 0, stream>>>(em, trn, pws, out);
    crf_finish<<<256, 256, 0, stream>>>(em, tags, mask, trn, stt, ent, pws, out);
}

// Round 5
// 247.857 us; speedup vs baseline: 1.8129x; 1.0758x over previous
//
#include <hip/hip_runtime.h>
#include <hip/hip_bf16.h>

#define Bb 256
#define Ss 2048
#define Tt 48
#define NCK 12           // chunks per batch (pws = 14.16 MB, round-3-proven size)
#define CLEN 171         // steps per chunk (last chunk: 166)

static constexpr float C_SHIFT = 4.875f;  // ~ln(48)+1: per-step growth ~= 1

typedef float f4   __attribute__((ext_vector_type(4)));
typedef short s4h  __attribute__((ext_vector_type(4)));
typedef __bf16 bf16x8 __attribute__((ext_vector_type(8)));

union U32x4 { unsigned u[4]; bf16x8 v; };
union U32x2 { unsigned u[2]; s4h v; };

__device__ __forceinline__ unsigned pk_trunc(float lo, float hi) {
    unsigned a = __builtin_bit_cast(unsigned, lo);
    unsigned b = __builtin_bit_cast(unsigned, hi);
#if __has_builtin(__builtin_amdgcn_perm)
    return __builtin_amdgcn_perm(b, a, 0x07060302u);
#else
    return (b & 0xFFFF0000u) | (a >> 16);
#endif
}
__device__ __forceinline__ unsigned pk_rne(float lo, float hi) {
    __hip_bfloat162 h = __float22bfloat162_rn(make_float2(lo, hi));
    union { __hip_bfloat16 b[2]; unsigned u; } t;
    t.b[0] = h.x; t.b[1] = h.y;
    return t.u;
}
__device__ __forceinline__ float bfu(unsigned u) { return __builtin_bit_cast(float, u); }

// k-slot bijection for the x32 operands: slot (g,j) holds k = sig(g,j).
// Chosen so the step's C-output (row = 16*mt + 4g + r at lane-quad g) repacks
// into next step's B operands with ZERO cross-lane traffic:
//   sig32(g,j) = 16*(j>>2) + 4g + (j&3)   (j<4 -> rows from m-tile 0, j>=4 -> m-tile 1)
//   x16 frag covers rows 32..47: slot (g,r) = 32 + 4g + r  (m-tile 2)
// A and B use the same slot convention, so the MFMA contracts correctly for
// ANY bijection (hardware pairs equal slots of A and B).
__device__ __forceinline__ int sig32(int g, int j) {
    return 16 * (j >> 2) + 4 * g + (j & 3);
}

#define MFMA32(a,b,c) __builtin_amdgcn_mfma_f32_16x16x32_bf16(a, b, c, 0, 0, 0)
#define MFMA16(a,b,c) __builtin_amdgcn_mfma_f32_16x16x16bf16_1k(a, b, c, 0, 0, 0)

// ---------------------------------------------------------------------------
// One scan step: per n-tile, D = A32*B32 (K=32 rows 0..31) + A16*B16 (rows
// 32..47), rowscale by e, repack (natural row space throughout).
// ---------------------------------------------------------------------------
__device__ __forceinline__ void scan_step(const bf16x8 (&A32)[3], const s4h (&A16)[3],
                                          bf16x8 (&B32)[3], s4h (&B16)[3],
                                          const float* __restrict__ eb)
{
    f4 e0 = *(const f4*)(eb);          // e[4g + 0..3]      (rows of m-tile 0)
    f4 e1 = *(const f4*)(eb + 16);     // e[16 + 4g + 0..3] (m-tile 1)
    f4 e2 = *(const f4*)(eb + 32);     // e[32 + 4g + 0..3] (m-tile 2)
    const f4 z = {0.f, 0.f, 0.f, 0.f};
#pragma unroll
    for (int nt = 0; nt < 3; ++nt) {
        f4 c0v = MFMA32(A32[0], B32[nt], z);
        f4 c1v = MFMA32(A32[1], B32[nt], z);
        f4 c2v = MFMA32(A32[2], B32[nt], z);
        c0v = MFMA16(A16[0], B16[nt], c0v);
        c1v = MFMA16(A16[1], B16[nt], c1v);
        c2v = MFMA16(A16[2], B16[nt], c2v);
        // repack: B32 slot j<4 <- m-tile0 reg j (row 4g+j); j>=4 <- m-tile1 reg j-4
        U32x4 nb;
        nb.u[0] = pk_trunc(c0v[0] * e0[0], c0v[1] * e0[1]);
        nb.u[1] = pk_trunc(c0v[2] * e0[2], c0v[3] * e0[3]);
        nb.u[2] = pk_trunc(c1v[0] * e1[0], c1v[1] * e1[1]);
        nb.u[3] = pk_trunc(c1v[2] * e1[2], c1v[3] * e1[3]);
        B32[nt] = nb.v;
        U32x2 nc;
        nc.u[0] = pk_trunc(c2v[0] * e2[0], c2v[1] * e2[1]);
        nc.u[1] = pk_trunc(c2v[2] * e2[2], c2v[3] * e2[3]);
        B16[nt] = nc.v;
    }
}

// ---------------------------------------------------------------------------
// Phase 1: one wave per (batch, chunk): 48x48 transfer-matrix product in regs.
// 768 blocks x 4 waves = 3072 waves = 256 batches x 12 chunks (3 blocks/CU).
// ---------------------------------------------------------------------------
__global__ __launch_bounds__(256, 3)
void crf_scan(const float* __restrict__ em, const float* __restrict__ trn,
              float* __restrict__ pws, float* __restrict__ outz)
{
    __shared__ float lex[4][16 * Tt];          // per-wave 16-step exp(em) buffer
    const int tid = threadIdx.x, wv = tid >> 6, l = tid & 63;
    const int c0 = l & 15, g = l >> 4;
    const int wid = blockIdx.x * 4 + wv;
    const int b = wid / NCK, ck = wid % NCK;
    if (blockIdx.x == 0 && tid == 0) outz[0] = 0.0f;   // zero d_out for finish

    // A-frags: A32[mt] slot (g,j) = E^T[16mt+c0][sig32(g,j)] = exp(trn[sig32(g,j)][16mt+c0])
    //          A16[mt] slot (g,j) = exp(trn[32+4g+j][16mt+c0])
    bf16x8 A32[3]; s4h A16[3];
#pragma unroll
    for (int mt = 0; mt < 3; ++mt) {
        float v[8];
#pragma unroll
        for (int j = 0; j < 8; ++j)
            v[j] = __expf(trn[sig32(g, j) * Tt + 16 * mt + c0]);
        U32x4 a;
        a.u[0] = pk_rne(v[0], v[1]); a.u[1] = pk_rne(v[2], v[3]);
        a.u[2] = pk_rne(v[4], v[5]); a.u[3] = pk_rne(v[6], v[7]);
        A32[mt] = a.v;
        float w0 = __expf(trn[(32 + 4 * g + 0) * Tt + 16 * mt + c0]);
        float w1 = __expf(trn[(32 + 4 * g + 1) * Tt + 16 * mt + c0]);
        float w2 = __expf(trn[(32 + 4 * g + 2) * Tt + 16 * mt + c0]);
        float w3 = __expf(trn[(32 + 4 * g + 3) * Tt + 16 * mt + c0]);
        U32x2 c;
        c.u[0] = pk_rne(w0, w1); c.u[1] = pk_rne(w2, w3);
        A16[mt] = c.v;
    }

    // State init = identity: B32 slot (g,j) = (sig32(g,j) == 16nt + c0)
    bf16x8 B32[3]; s4h B16[3];
#pragma unroll
    for (int nt = 0; nt < 3; ++nt) {
        U32x4 bi;
#pragma unroll
        for (int q = 0; q < 4; ++q) {
            unsigned lo = (sig32(g, 2 * q)     == 16 * nt + c0) ? 0x3F80u : 0u;
            unsigned hi = (sig32(g, 2 * q + 1) == 16 * nt + c0) ? 0x3F80u : 0u;
            bi.u[q] = lo | (hi << 16);
        }
        B32[nt] = bi.v;
        U32x2 ci;
#pragma unroll
        for (int q = 0; q < 2; ++q) {
            unsigned lo = (nt == 2 && 4 * g + 2 * q     == c0) ? 0x3F80u : 0u;
            unsigned hi = (nt == 2 && 4 * g + 2 * q + 1 == c0) ? 0x3F80u : 0u;
            ci.u[q] = lo | (hi << 16);
        }
        B16[nt] = ci.v;
    }

    const int total = (ck == NCK - 1) ? (Ss - 1 - ck * CLEN) : CLEN;  // 171 / 166
    const int s0 = ck * CLEN + 1;
    const float* emb = em + (size_t)b * (Ss * Tt);
    float* lw = &lex[wv][0];
    const float* lexg = lw + g * 4;
    const long lim = (long)Ss * Tt - 4;

    // prefetch sub 0 (early-issued global loads, consumed at loop top)
    f4 r[3];
#pragma unroll
    for (int i = 0; i < 3; ++i) {
        long o = (long)s0 * Tt + l * 4 + i * 256;
        if (o > lim) o = lim;
        r[i] = *(const f4*)(emb + o);
    }

    const int nsub = (total + 15) >> 4;
    for (int sub = 0; sub < nsub; ++sub) {
#pragma unroll
        for (int i = 0; i < 3; ++i)
#pragma unroll
            for (int j = 0; j < 4; ++j) r[i][j] = __expf(r[i][j] - C_SHIFT);
#pragma unroll
        for (int i = 0; i < 3; ++i) *(f4*)(lw + l * 4 + i * 256) = r[i];

        if (sub + 1 < nsub) {        // issue next sub's loads before compute
#pragma unroll
            for (int i = 0; i < 3; ++i) {
                long o = (long)(s0 + (sub + 1) * 16) * Tt + l * 4 + i * 256;
                if (o > lim) o = lim;
                r[i] = *(const f4*)(emb + o);
            }
        }

        int nsteps = total - sub * 16;
        if (nsteps >= 16) {
#pragma unroll
            for (int u = 0; u < 16; ++u)
                scan_step(A32, A16, B32, B16, lexg + u * Tt);
        } else {
            for (int u = 0; u < nsteps; ++u)
                scan_step(A32, A16, B32, B16, lexg + u * Tt);
        }
    }

    // store 18 u32/lane, coalesced. Row content per lane-quad g:
    //   u-offset q=0..3: rows {sig32(g,2q), sig32(g,2q+1)} ; q=4,5: rows 32+4g+{2q',2q'+1}
    unsigned* pw = (unsigned*)pws + (size_t)wid * 1152 + l;
#pragma unroll
    for (int nt = 0; nt < 3; ++nt) {
        U32x4 a; a.v = B32[nt];
        U32x2 c; c.v = B16[nt];
        pw[(nt * 6 + 0) * 64] = a.u[0];
        pw[(nt * 6 + 1) * 64] = a.u[1];
        pw[(nt * 6 + 2) * 64] = a.u[2];
        pw[(nt * 6 + 3) * 64] = a.u[3];
        pw[(nt * 6 + 4) * 64] = c.u[0];
        pw[(nt * 6 + 5) * 64] = c.u[1];
    }
}

// ---------------------------------------------------------------------------
// Phase 2 + gold, merged: one block per batch; wave 0 chains the 12 chunk
// matrices with renorm, combines with gold. Natural row space: stored word
// (nt*6+q)*64 at lane (g,c0) holds rows 16t+4g+{2r,2r+1} col 16nt+c0, where
// q=0..3 -> t=0 (q<2) / t=1 (q>=2), q=4,5 -> t=2.  I.e. y[4t+r] <-> row 16t+4g+r.
// ---------------------------------------------------------------------------
__global__ __launch_bounds__(256)
void crf_finish(const float* __restrict__ em, const int* __restrict__ tags,
                const int* __restrict__ mask, const float* __restrict__ trn,
                const float* __restrict__ stt, const float* __restrict__ ent,
                const float* __restrict__ pws, float* __restrict__ out)
{
    __shared__ float red[256];
    __shared__ float alpha[Tt];
    const int b = blockIdx.x, t = threadIdx.x;

    // gold partial
    const int* tg = tags + (size_t)b * Ss;
    float local = 0.0f;
    for (int s = t; s < Ss; s += 256) {
        if (s > 0) {
            int pv = tg[s - 1], cu = tg[s];
            float mf = (float)mask[(size_t)b * Ss + s];
            local += (trn[pv * Tt + cu] + em[((size_t)b * Ss + s) * Tt + cu]) * mf;
        }
    }
    if (t == 0) {
        int t0 = tg[0];
        local += stt[t0] + em[(size_t)b * Ss * Tt + t0];
        local += ent[tg[Ss - 1]];
    }
    red[t] = local;
    __syncthreads();
    if (t < 128) red[t] += red[t + 128];
    __syncthreads();

    if (t < 64) {
        const int l = t, c0 = l & 15, g = l >> 4;
        float gsum = red[l] + red[l + 64];
#pragma unroll
        for (int m = 32; m >= 1; m >>= 1) gsum += __shfl_xor(gsum, m);

        // alpha init (natural): alpha[i] = exp(stt[i] + em[b,0,i] - C)
        if (l < Tt) alpha[l] = __expf(stt[l] + em[(size_t)b * Ss * Tt + l] - C_SHIFT);

        float acc = 0.0f;
        const unsigned* pw = (const unsigned*)pws + (size_t)b * NCK * 1152 + l;
        for (int ck = 0; ck < NCK; ++ck) {
            float y[12];
#pragma unroll
            for (int i = 0; i < 12; ++i) y[i] = 0.0f;
#pragma unroll
            for (int nt = 0; nt < 3; ++nt) {
                float av = alpha[16 * nt + c0];
                unsigned w[6];
#pragma unroll
                for (int q = 0; q < 6; ++q) w[q] = pw[(size_t)ck * 1152 + (nt * 6 + q) * 64];
                // q=0,1 -> y[0..3] (rows 4g+r); q=2,3 -> y[4..7] (16+4g+r); q=4,5 -> y[8..11]
#pragma unroll
                for (int q = 0; q < 6; ++q) {
                    y[2 * q]     += bfu(w[q] << 16)         * av;
                    y[2 * q + 1] += bfu(w[q] & 0xFFFF0000u) * av;
                }
            }
#pragma unroll
            for (int m = 1; m <= 8; m <<= 1)
#pragma unroll
                for (int i = 0; i < 12; ++i) y[i] += __shfl_xor(y[i], m);
            float mx = y[0];
#pragma unroll
            for (int i = 1; i < 12; ++i) mx = fmaxf(mx, y[i]);
            mx = fmaxf(mx, __shfl_xor(mx, 16));
            mx = fmaxf(mx, __shfl_xor(mx, 32));
            acc += __logf(mx);
            float rm = 1.0f / mx;
            if (c0 == 0) {
#pragma unroll
                for (int tt = 0; tt < 3; ++tt)
#pragma unroll
                    for (int rr = 0; rr < 4; ++rr)
                        alpha[16 * tt + 4 * g + rr] = y[4 * tt + rr] * rm;
            }
        }
        // fwd = log(sum alpha * exp(ent)) + acc + S*C
        float part = (l < Tt) ? alpha[l] * __expf(ent[l]) : 0.0f;
#pragma unroll
        for (int m = 32; m >= 1; m >>= 1) part += __shfl_xor(part, m);
        if (t == 0) {
            float fwd = __logf(part) + acc + (float)Ss * C_SHIFT;
            atomicAdd(out, (fwd - gsum) * (1.0f / 256.0f));
        }
    }
}

// ---------------------------------------------------------------------------
extern "C" void kernel_launch(void* const* d_in, const int* in_sizes, int n_in,
                              void* d_out, int out_size, void* d_ws, size_t ws_size,
                              hipStream_t stream)
{
    const float* em  = (const float*)d_in[0];
    const int* tags  = (const int*)d_in[1];
    const int* mask  = (const int*)d_in[2];
    const float* trn = (const float*)d_in[3];
    const float* stt = (const float*)d_in[4];
    const float* ent = (const float*)d_in[5];
    float* out = (float*)d_out;
    float* pws = (float*)d_ws;   // 3072 waves x 1152 u32 = 14.16 MB (proven safe)

    crf_scan<<<768, 256, 0, stream>>>(em, trn, pws, out);
    crf_finish<<<256, 256, 0, stream>>>(em, tags, mask, trn, stt, ent, pws, out);
}